// Round 8
// baseline (514.145 us; speedup 1.0000x reference)
//
#include <hip/hip_runtime.h>
#include <hip/hip_bf16.h>

typedef __attribute__((ext_vector_type(8))) __bf16 bf16x8;
typedef __attribute__((ext_vector_type(4))) float f32x4;

#define BATCH 16
#define LSEQ 2048
#define DIM 128
#define EPITCH 2056
#define NKBLK 64   // 2048 / 32

__device__ __forceinline__ bf16x8 cvt8(float4 a, float4 b) {
    bf16x8 r;
    r[0] = (__bf16)a.x; r[1] = (__bf16)a.y; r[2] = (__bf16)a.z; r[3] = (__bf16)a.w;
    r[4] = (__bf16)b.x; r[5] = (__bf16)b.y; r[6] = (__bf16)b.z; r[7] = (__bf16)b.w;
    return r;
}

// ============ preproc: K -> fragment-blocked Kf[b][kblk][j][lane] ============
// j = t*4+d ; lane = g*16+li ; unit (bf16x8) = K[b][kblk*32 + t*16 + li][d*32 + g*8 + e]
__global__ __launch_bounds__(256)
void pack_k_kernel(const float* __restrict__ kg, bf16x8* __restrict__ kf) {
    __shared__ __bf16 Ks[32][DIM + 8];
    const int kblk = blockIdx.x, b = blockIdx.y;
    const int tid = threadIdx.x;
    {
        const int r = tid >> 3, c4 = tid & 7;
        const float* src = kg + ((size_t)b * LSEQ + kblk * 32 + r) * DIM;
        #pragma unroll
        for (int jj = 0; jj < 4; ++jj) {
            const int c = (c4 + 8 * jj) * 4;
            float4 x = *reinterpret_cast<const float4*>(src + c);
            Ks[r][c + 0] = (__bf16)x.x; Ks[r][c + 1] = (__bf16)x.y;
            Ks[r][c + 2] = (__bf16)x.z; Ks[r][c + 3] = (__bf16)x.w;
        }
    }
    __syncthreads();
    const int lane = tid & 63, w = tid >> 6;
    const int g = lane >> 4, li = lane & 15;
    bf16x8* dst = kf + ((size_t)b * NKBLK + kblk) * 8 * 64;
    #pragma unroll
    for (int jj = 0; jj < 2; ++jj) {
        const int j = 2 * w + jj;
        const int t = j >> 2, d = j & 3;
        bf16x8 v;
        #pragma unroll
        for (int e = 0; e < 8; ++e) v[e] = Ks[t * 16 + li][d * 32 + g * 8 + e];
        dst[j * 64 + lane] = v;
    }
}

// ============ preproc: V -> fragment-blocked Vf[b][kblk][dt][lane] ============
// unit (bf16x8) = V[b][kblk*32 + g*8 + e][dt*16 + li]
__global__ __launch_bounds__(256)
void pack_v_kernel(const float* __restrict__ vg, bf16x8* __restrict__ vf) {
    __shared__ __bf16 Vs[32][DIM + 8];
    const int kblk = blockIdx.x, b = blockIdx.y;
    const int tid = threadIdx.x;
    {
        const int r = tid >> 3, c4 = tid & 7;
        const float* src = vg + ((size_t)b * LSEQ + kblk * 32 + r) * DIM;
        #pragma unroll
        for (int jj = 0; jj < 4; ++jj) {
            const int c = (c4 + 8 * jj) * 4;
            float4 x = *reinterpret_cast<const float4*>(src + c);
            Vs[r][c + 0] = (__bf16)x.x; Vs[r][c + 1] = (__bf16)x.y;
            Vs[r][c + 2] = (__bf16)x.z; Vs[r][c + 3] = (__bf16)x.w;
        }
    }
    __syncthreads();
    const int lane = tid & 63, w = tid >> 6;
    const int g = lane >> 4, li = lane & 15;
    bf16x8* dst = vf + ((size_t)b * NKBLK + kblk) * 8 * 64;
    #pragma unroll
    for (int jj = 0; jj < 2; ++jj) {
        const int dt = 2 * w + jj;
        bf16x8 v;
        #pragma unroll
        for (int e = 0; e < 8; ++e) v[e] = Vs[g * 8 + e][dt * 16 + li];
        dst[dt * 64 + lane] = v;
    }
}

// ============ preproc: mask -> per-wave bytes mp[b][qt16][kblk][lane] ============
// bit (t*4+r) = mask[b][qt16*16 + g*4 + r][kblk*32 + t*16 + li]
__global__ __launch_bounds__(256)
void pack_mask_kernel(const int* __restrict__ maskg, unsigned char* __restrict__ mp) {
    __shared__ unsigned ball[16][64];   // [q][k/32]
    const int tid  = threadIdx.x;
    const int wave = tid >> 6;
    const int lane = tid & 63;
    const int g    = lane >> 4;
    const int li   = lane & 15;
    const int qt   = blockIdx.x;   // 0..127
    const int b    = blockIdx.y;

    const int* mb = maskg + ((size_t)b * LSEQ + qt * 16) * LSEQ;
    #pragma unroll
    for (int qq = 0; qq < 4; ++qq) {
        const int q = wave * 4 + qq;
        #pragma unroll 8
        for (int c = 0; c < 32; ++c) {
            int m = mb[(size_t)q * LSEQ + c * 64 + lane];
            unsigned long long bal = __ballot(m != 0);
            if (lane == 0) {
                ball[q][c * 2]     = (unsigned)bal;
                ball[q][c * 2 + 1] = (unsigned)(bal >> 32);
            }
        }
    }
    __syncthreads();
    unsigned char* out = mp + ((size_t)b * 128 + qt) * (NKBLK * 64) + lane;
    for (int kb2 = wave; kb2 < NKBLK; kb2 += 4) {
        unsigned byte = 0;
        #pragma unroll
        for (int r = 0; r < 4; ++r) {
            unsigned wd = ball[g * 4 + r][kb2];
            byte |= ((wd >> li) & 1u) << r;
            byte |= ((wd >> (16 + li)) & 1u) << (4 + r);
        }
        out[(size_t)kb2 * 64] = (unsigned char)byte;
    }
}

// ============ attn32q: 32 q/block, waves split over k, blocked E dump ============
__global__ __launch_bounds__(512, 2)
void attn32q(const float* __restrict__ qg,
             const bf16x8* __restrict__ kf,
             const bf16x8* __restrict__ vf,
             const unsigned char* __restrict__ mpk,
             float* __restrict__ og,
             float* __restrict__ rowinv_ws,
             __bf16* __restrict__ Eg)
{
    __shared__ __align__(16) __bf16 P[8][2][16][40];   // 20.5 KB
    __shared__ float Osum[32 * DIM];                   // 16 KB
    __shared__ float rowpart[8][32];
    __shared__ float rowinv[32];

    const int tid  = threadIdx.x;
    const int wave = tid >> 6;     // 0..7 : k-slab owner
    const int lane = tid & 63;
    const int g    = lane >> 4;
    const int li   = lane & 15;

    // XCD pinning: 1024 blocks; batch b on xcd b%8
    const int wgid = blockIdx.x;            // 0..1023
    const int xcd  = wgid & 7;
    const int rest = wgid >> 3;             // 0..127
    const int b    = xcd + 8 * (rest & 1);
    const int qt32 = rest >> 1;             // 0..63
    const int q0   = qt32 * 32;

    const size_t bb = (size_t)b * LSEQ;

    // zero O accumulator (ordered before atomics by the post-loop barrier)
    for (int i = tid; i < 32 * DIM; i += 512) Osum[i] = 0.0f;

    // Q fragments for 2 tiles, scale*log2(e) folded
    const float qscale = 0.08838834764831845f * 1.4426950408889634f;
    bf16x8 qf[2][4];
    #pragma unroll
    for (int tl = 0; tl < 2; ++tl) {
        const float* qrow = qg + (bb + q0 + tl * 16 + li) * DIM + g * 8;
        #pragma unroll
        for (int d = 0; d < 4; ++d) {
            const float4* p4 = reinterpret_cast<const float4*>(qrow + d * 32);
            float4 x = p4[0];
            float4 y = p4[1];
            x.x *= qscale; x.y *= qscale; x.z *= qscale; x.w *= qscale;
            y.x *= qscale; y.y *= qscale; y.z *= qscale; y.w *= qscale;
            qf[tl][d] = cvt8(x, y);
        }
    }

    float rsum[2][4];
    #pragma unroll
    for (int tl = 0; tl < 2; ++tl)
        #pragma unroll
        for (int r = 0; r < 4; ++r) rsum[tl][r] = 0.0f;
    f32x4 accO[2][8];
    #pragma unroll
    for (int tl = 0; tl < 2; ++tl)
        #pragma unroll
        for (int i = 0; i < 8; ++i) accO[tl][i] = (f32x4){0.f, 0.f, 0.f, 0.f};

    const bf16x8* Kb = kf + (size_t)b * NKBLK * 8 * 64 + lane;
    const bf16x8* Vb = vf + (size_t)b * NKBLK * 8 * 64 + lane;
    const unsigned char* mp0 = mpk + ((size_t)b * 128 + qt32 * 2)     * (NKBLK * 64) + lane;
    const unsigned char* mp1 = mpk + ((size_t)b * 128 + qt32 * 2 + 1) * (NKBLK * 64) + lane;

    const int kslab0 = wave * 8;   // this wave's 8 kblks

    for (int it = 0; it < 8; ++it) {
        const int kblk = kslab0 + it;

        // coalesced fragment loads (single-segment 1KB each)
        bf16x8 kc[8], vc[8];
        #pragma unroll
        for (int j = 0; j < 8; ++j) kc[j] = Kb[((size_t)kblk * 8 + j) * 64];
        #pragma unroll
        for (int dt = 0; dt < 8; ++dt) vc[dt] = Vb[((size_t)kblk * 8 + dt) * 64];
        const unsigned m0 = mp0[(size_t)kblk * 64];
        const unsigned m1 = mp1[(size_t)kblk * 64];

        // QK^T: 2 q-tiles share K fragments
        f32x4 s[2][2];
        #pragma unroll
        for (int tl = 0; tl < 2; ++tl)
            #pragma unroll
            for (int t = 0; t < 2; ++t) s[tl][t] = (f32x4){0.f, 0.f, 0.f, 0.f};
        #pragma unroll
        for (int d = 0; d < 4; ++d) {
            s[0][0] = __builtin_amdgcn_mfma_f32_16x16x32_bf16(qf[0][d], kc[d],     s[0][0], 0, 0, 0);
            s[0][1] = __builtin_amdgcn_mfma_f32_16x16x32_bf16(qf[0][d], kc[4 + d], s[0][1], 0, 0, 0);
            s[1][0] = __builtin_amdgcn_mfma_f32_16x16x32_bf16(qf[1][d], kc[d],     s[1][0], 0, 0, 0);
            s[1][1] = __builtin_amdgcn_mfma_f32_16x16x32_bf16(qf[1][d], kc[4 + d], s[1][1], 0, 0, 0);
        }

        // mask + exp2 + P stage + rowsum
        #pragma unroll
        for (int tl = 0; tl < 2; ++tl) {
            const unsigned mb_ = tl ? m1 : m0;
            #pragma unroll
            for (int t = 0; t < 2; ++t) {
                #pragma unroll
                for (int r = 0; r < 4; ++r) {
                    float sc = ((mb_ >> (t * 4 + r)) & 1u) ? -1.0e9f : s[tl][t][r];
                    float ev = __builtin_amdgcn_exp2f(sc);
                    rsum[tl][r] += ev;
                    P[wave][tl][g * 4 + r][t * 16 + li] = (__bf16)ev;
                }
            }
        }

        // blocked E dump: one contiguous 1KB unit per (q-tile, kblk), nt store
        #pragma unroll
        for (int tl = 0; tl < 2; ++tl) {
            bf16x8 ed = *reinterpret_cast<const bf16x8*>(&P[wave][tl][lane >> 2][(lane & 3) * 8]);
            __bf16* dst = Eg + (((size_t)b * 128 + qt32 * 2 + tl) * 64 + kblk) * 512 + lane * 8;
            __builtin_nontemporal_store(ed, reinterpret_cast<bf16x8*>(dst));
        }

        // PV: 2 q-tiles share V fragments
        {
            bf16x8 af0 = *reinterpret_cast<const bf16x8*>(&P[wave][0][li][g * 8]);
            bf16x8 af1 = *reinterpret_cast<const bf16x8*>(&P[wave][1][li][g * 8]);
            #pragma unroll
            for (int dt = 0; dt < 8; ++dt) {
                accO[0][dt] = __builtin_amdgcn_mfma_f32_16x16x32_bf16(af0, vc[dt], accO[0][dt], 0, 0, 0);
                accO[1][dt] = __builtin_amdgcn_mfma_f32_16x16x32_bf16(af1, vc[dt], accO[1][dt], 0, 0, 0);
            }
        }
    }

    // per-wave rowsum reduce across li lanes
    #pragma unroll
    for (int off = 1; off < 16; off <<= 1) {
        #pragma unroll
        for (int tl = 0; tl < 2; ++tl)
            #pragma unroll
            for (int r = 0; r < 4; ++r) rsum[tl][r] += __shfl_xor(rsum[tl][r], off, 64);
    }
    if (li == 0) {
        #pragma unroll
        for (int tl = 0; tl < 2; ++tl)
            #pragma unroll
            for (int r = 0; r < 4; ++r) rowpart[wave][tl * 16 + g * 4 + r] = rsum[tl][r];
    }
    __syncthreads();   // orders Osum zero-init + rowpart before atomics/reads

    // combine O partials across waves
    #pragma unroll
    for (int tl = 0; tl < 2; ++tl)
        #pragma unroll
        for (int dt = 0; dt < 8; ++dt)
            #pragma unroll
            for (int r = 0; r < 4; ++r)
                atomicAdd(&Osum[(tl * 16 + g * 4 + r) * DIM + dt * 16 + li], accO[tl][dt][r]);
    if (tid < 32) {
        float s = 0.0f;
        #pragma unroll
        for (int w8 = 0; w8 < 8; ++w8) s += rowpart[w8][tid];
        float inv = 1.0f / s;
        rowinv[tid] = inv;
        rowinv_ws[bb + q0 + tid] = inv;
    }
    __syncthreads();

    // O write: coalesced float4 nt
    {
        float* ob = og + (bb + q0) * DIM;
        const f32x4* os4 = reinterpret_cast<const f32x4*>(Osum);
        for (int i4 = tid; i4 < 32 * DIM / 4; i4 += 512) {
            const int row = i4 >> 5;
            f32x4 x = os4[i4];
            const float inv = rowinv[row];
            x[0] *= inv; x[1] *= inv; x[2] *= inv; x[3] *= inv;
            __builtin_nontemporal_store(x, reinterpret_cast<f32x4*>(ob + i4 * 4));
        }
    }
}

// ============ wstream: blocked E -> LDS transpose -> row-major W ============
__global__ __launch_bounds__(512)
void wstream(const __bf16* __restrict__ Eg,
             const float* __restrict__ rowinv_ws,
             float* __restrict__ wg)
{
    __shared__ __align__(16) __bf16 Es[16 * EPITCH];   // 65.8 KB
    __shared__ float rowinvS[16];

    const int tid  = threadIdx.x;
    const int bx   = blockIdx.x;        // 0..2047
    const int b    = bx >> 7;
    const int qt16 = bx & 127;

    if (tid < 16)
        rowinvS[tid] = rowinv_ws[(size_t)b * LSEQ + qt16 * 16 + tid];

    // read blocked E (fully coalesced), scatter to row-major LDS
    const __bf16* src = Eg + ((size_t)b * 128 + qt16) * 64 * 512;
    #pragma unroll
    for (int i = 0; i < 8; ++i) {
        const int c    = i * 512 + tid;       // 16B-chunk index, 0..4095
        const int kblk = c >> 6;
        const int lane = c & 63;
        const int row  = lane >> 2;
        const int col  = kblk * 32 + (lane & 3) * 8;
        bf16x8 e = __builtin_nontemporal_load(
            reinterpret_cast<const bf16x8*>(src + (size_t)c * 8));
        *reinterpret_cast<bf16x8*>(&Es[row * EPITCH + col]) = e;
    }
    __syncthreads();

    // write W row-major, coalesced, nt
    float* wrow = wg + ((size_t)b * LSEQ + qt16 * 16) * LSEQ;
    #pragma unroll
    for (int i = 0; i < 8; ++i) {
        const int idx8 = (i * 512 + tid) * 8;     // 16*2048 elems / 8
        const int row  = idx8 >> 11;
        const int col  = idx8 & 2047;
        bf16x8 e = *reinterpret_cast<const bf16x8*>(&Es[row * EPITCH + col]);
        const float inv = rowinvS[row];
        f32x4 w0, w1;
        w0[0] = (float)e[0] * inv; w0[1] = (float)e[1] * inv;
        w0[2] = (float)e[2] * inv; w0[3] = (float)e[3] * inv;
        w1[0] = (float)e[4] * inv; w1[1] = (float)e[5] * inv;
        w1[2] = (float)e[6] * inv; w1[3] = (float)e[7] * inv;
        float* dst = wrow + (size_t)row * LSEQ + col;
        __builtin_nontemporal_store(w0, reinterpret_cast<f32x4*>(dst));
        __builtin_nontemporal_store(w1, reinterpret_cast<f32x4*>(dst + 4));
    }
}

// ========================= fallback (no workspace) =========================
__global__ __launch_bounds__(256, 2)
void sdpa_fused_plain(const float* __restrict__ qg,
                      const float* __restrict__ kg,
                      const float* __restrict__ vg,
                      const int*   __restrict__ maskg,
                      float* __restrict__ og,
                      float* __restrict__ wg)
{
    __shared__ __align__(16) __bf16 Es[16 * EPITCH];
    __shared__ float Osum[16 * DIM];
    __shared__ float rowpart[4][16];
    __shared__ float rowinv[16];

    const int tid  = threadIdx.x;
    const int wave = tid >> 6;
    const int lane = tid & 63;
    const int g    = lane >> 4;
    const int li   = lane & 15;
    const int qt = blockIdx.x;
    const int b  = blockIdx.y;
    const int q0 = qt * 16;

    for (int i = tid; i < 16 * DIM; i += 256) Osum[i] = 0.0f;

    const float qscale = 0.08838834764831845f * 1.4426950408889634f;
    bf16x8 qf[4];
    {
        const float* qrow = qg + ((size_t)b * LSEQ + q0 + li) * DIM + g * 8;
        #pragma unroll
        for (int d = 0; d < 4; ++d) {
            const float4* p4 = reinterpret_cast<const float4*>(qrow + d * 32);
            float4 x = p4[0];
            float4 y = p4[1];
            x.x *= qscale; x.y *= qscale; x.z *= qscale; x.w *= qscale;
            y.x *= qscale; y.y *= qscale; y.z *= qscale; y.w *= qscale;
            qf[d] = cvt8(x, y);
        }
    }

    float rsum[4] = {0.f, 0.f, 0.f, 0.f};
    f32x4 accO[8];
    #pragma unroll
    for (int i = 0; i < 8; ++i) accO[i] = (f32x4){0.f, 0.f, 0.f, 0.f};

    const int kwave0 = wave * 512;
    const size_t browbase = (size_t)b * LSEQ;

    for (int it = 0; it < 16; ++it) {
        const int kb = kwave0 + it * 32;
        f32x4 s0 = (f32x4){0.f, 0.f, 0.f, 0.f};
        f32x4 s1 = (f32x4){0.f, 0.f, 0.f, 0.f};
        {
            const float* kp0 = kg + (browbase + kb + li) * DIM + g * 8;
            const float* kp1 = kp0 + (size_t)16 * DIM;
            #pragma unroll
            for (int d = 0; d < 4; ++d) {
                const float4* a4 = reinterpret_cast<const float4*>(kp0 + d * 32);
                const float4* b4 = reinterpret_cast<const float4*>(kp1 + d * 32);
                s0 = __builtin_amdgcn_mfma_f32_16x16x32_bf16(qf[d], cvt8(a4[0], a4[1]), s0, 0, 0, 0);
                s1 = __builtin_amdgcn_mfma_f32_16x16x32_bf16(qf[d], cvt8(b4[0], b4[1]), s1, 0, 0, 0);
            }
        }
        const int* mbase = maskg + (browbase + q0) * LSEQ + kb + li;
        #pragma unroll
        for (int t = 0; t < 2; ++t) {
            f32x4 sv = t ? s1 : s0;
            const int col = kb + t * 16 + li;
            #pragma unroll
            for (int r = 0; r < 4; ++r) {
                const int m = mbase[(size_t)(g * 4 + r) * LSEQ + t * 16];
                float sc = m ? -1.0e9f : sv[r];
                float ev = __builtin_amdgcn_exp2f(sc);
                rsum[r] += ev;
                Es[(g * 4 + r) * EPITCH + col] = (__bf16)ev;
            }
        }
        bf16x8 af = *reinterpret_cast<const bf16x8*>(&Es[li * EPITCH + kb + g * 8]);
        const float* vb = vg + (browbase + kb + g * 8) * DIM + li;
        #pragma unroll
        for (int dt = 0; dt < 8; ++dt) {
            const float* vp = vb + dt * 16;
            bf16x8 bf;
            #pragma unroll
            for (int j = 0; j < 8; ++j) bf[j] = (__bf16)vp[(size_t)j * DIM];
            accO[dt] = __builtin_amdgcn_mfma_f32_16x16x32_bf16(af, bf, accO[dt], 0, 0, 0);
        }
    }

    #pragma unroll
    for (int off = 1; off < 16; off <<= 1) {
        #pragma unroll
        for (int r = 0; r < 4; ++r) rsum[r] += __shfl_xor(rsum[r], off, 64);
    }
    if (li == 0) {
        #pragma unroll
        for (int r = 0; r < 4; ++r) rowpart[wave][g * 4 + r] = rsum[r];
    }
    __syncthreads();
    #pragma unroll
    for (int dt = 0; dt < 8; ++dt) {
        #pragma unroll
        for (int r = 0; r < 4; ++r)
            atomicAdd(&Osum[(g * 4 + r) * DIM + dt * 16 + li], accO[dt][r]);
    }
    if (tid < 16) {
        float s = rowpart[0][tid] + rowpart[1][tid] + rowpart[2][tid] + rowpart[3][tid];
        rowinv[tid] = 1.0f / s;
    }
    __syncthreads();

    const size_t wbase = (browbase + q0) * LSEQ;
    for (int i = tid; i < 16 * (LSEQ / 8); i += 256) {
        const int row = i >> 8;
        const int col = (i & 255) * 8;
        bf16x8 e = *reinterpret_cast<const bf16x8*>(&Es[row * EPITCH + col]);
        const float inv = rowinv[row];
        float4 w0, w1;
        w0.x = (float)e[0] * inv; w0.y = (float)e[1] * inv;
        w0.z = (float)e[2] * inv; w0.w = (float)e[3] * inv;
        w1.x = (float)e[4] * inv; w1.y = (float)e[5] * inv;
        w1.z = (float)e[6] * inv; w1.w = (float)e[7] * inv;
        float* dst = wg + wbase + (size_t)row * LSEQ + col;
        *reinterpret_cast<float4*>(dst)     = w0;
        *reinterpret_cast<float4*>(dst + 4) = w1;
    }
    const size_t obase = (browbase + q0) * DIM;
    for (int i = tid; i < 16 * DIM; i += 256) {
        const int row = i >> 7;
        og[obase + i] = Osum[i] * rowinv[row];
    }
}

extern "C" void kernel_launch(void* const* d_in, const int* in_sizes, int n_in,
                              void* d_out, int out_size, void* d_ws, size_t ws_size,
                              hipStream_t stream) {
    const float* q    = (const float*)d_in[0];
    const float* k    = (const float*)d_in[1];
    const float* v    = (const float*)d_in[2];
    const int*   mask = (const int*)d_in[3];
    float* o = (float*)d_out;
    float* w = (float*)d_out + (size_t)BATCH * LSEQ * DIM;

    const size_t kfSize = (size_t)BATCH * NKBLK * 8 * 64 * sizeof(bf16x8);   // 8.4 MB
    const size_t vfSize = kfSize;                                            // 8.4 MB
    const size_t mpSize = (size_t)BATCH * 128 * NKBLK * 64;                  // 8.4 MB
    const size_t riSize = (size_t)BATCH * LSEQ * sizeof(float);              // 131 KB
    const size_t eSize  = (size_t)BATCH * LSEQ * LSEQ * sizeof(__bf16);      // 134 MB
    const size_t need   = kfSize + vfSize + mpSize + riSize + eSize;

    if (ws_size >= need) {
        bf16x8* kf = (bf16x8*)d_ws;
        bf16x8* vfp = (bf16x8*)((char*)d_ws + kfSize);
        unsigned char* mp = (unsigned char*)((char*)d_ws + kfSize + vfSize);
        float* ri = (float*)((char*)d_ws + kfSize + vfSize + mpSize);
        __bf16* Eg = (__bf16*)((char*)d_ws + kfSize + vfSize + mpSize + riSize);
        pack_k_kernel<<<dim3(NKBLK, BATCH), 256, 0, stream>>>(k, kf);
        pack_v_kernel<<<dim3(NKBLK, BATCH), 256, 0, stream>>>(v, vfp);
        pack_mask_kernel<<<dim3(128, BATCH), 256, 0, stream>>>(mask, mp);
        attn32q<<<1024, 512, 0, stream>>>(q, kf, vfp, mp, o, ri, Eg);
        wstream<<<BATCH * 128, 512, 0, stream>>>(Eg, ri, w);
    } else {
        dim3 grid(LSEQ / 16, BATCH);
        sdpa_fused_plain<<<grid, 256, 0, stream>>>(q, k, v, mask, o, w);
    }
}

// Round 9
// 261.040 us; speedup vs baseline: 1.9696x; 1.9696x over previous
//
#include <hip/hip_runtime.h>
#include <hip/hip_bf16.h>

typedef __attribute__((ext_vector_type(8))) __bf16 bf16x8;
typedef __attribute__((ext_vector_type(4))) float f32x4;

#define BATCH 16
#define LSEQ 2048
#define DIM 128
#define EPITCH 2056
#define NKBLK 64   // 2048 / 32

__device__ __forceinline__ bf16x8 cvt8(float4 a, float4 b) {
    bf16x8 r;
    r[0] = (__bf16)a.x; r[1] = (__bf16)a.y; r[2] = (__bf16)a.z; r[3] = (__bf16)a.w;
    r[4] = (__bf16)b.x; r[5] = (__bf16)b.y; r[6] = (__bf16)b.z; r[7] = (__bf16)b.w;
    return r;
}

// ============ preproc: K -> fragment-blocked Kf[b][kblk][j][lane] ============
// j = t*4+d ; lane = g*16+li ; unit (bf16x8) = K[b][kblk*32 + t*16 + li][d*32 + g*8 + e]
__global__ __launch_bounds__(256)
void pack_k_kernel(const float* __restrict__ kg, bf16x8* __restrict__ kf) {
    __shared__ __bf16 Ks[32][DIM + 8];
    const int kblk = blockIdx.x, b = blockIdx.y;
    const int tid = threadIdx.x;
    {
        const int r = tid >> 3, c4 = tid & 7;
        const float* src = kg + ((size_t)b * LSEQ + kblk * 32 + r) * DIM;
        #pragma unroll
        for (int jj = 0; jj < 4; ++jj) {
            const int c = (c4 + 8 * jj) * 4;
            float4 x = *reinterpret_cast<const float4*>(src + c);
            Ks[r][c + 0] = (__bf16)x.x; Ks[r][c + 1] = (__bf16)x.y;
            Ks[r][c + 2] = (__bf16)x.z; Ks[r][c + 3] = (__bf16)x.w;
        }
    }
    __syncthreads();
    const int lane = tid & 63, w = tid >> 6;
    const int g = lane >> 4, li = lane & 15;
    bf16x8* dst = kf + ((size_t)b * NKBLK + kblk) * 8 * 64;
    #pragma unroll
    for (int jj = 0; jj < 2; ++jj) {
        const int j = 2 * w + jj;
        const int t = j >> 2, d = j & 3;
        bf16x8 v;
        #pragma unroll
        for (int e = 0; e < 8; ++e) v[e] = Ks[t * 16 + li][d * 32 + g * 8 + e];
        dst[j * 64 + lane] = v;
    }
}

// ============ preproc: V -> fragment-blocked Vf[b][kblk][dt][lane] ============
// unit (bf16x8) = V[b][kblk*32 + g*8 + e][dt*16 + li]
__global__ __launch_bounds__(256)
void pack_v_kernel(const float* __restrict__ vg, bf16x8* __restrict__ vf) {
    __shared__ __bf16 Vs[32][DIM + 8];
    const int kblk = blockIdx.x, b = blockIdx.y;
    const int tid = threadIdx.x;
    {
        const int r = tid >> 3, c4 = tid & 7;
        const float* src = vg + ((size_t)b * LSEQ + kblk * 32 + r) * DIM;
        #pragma unroll
        for (int jj = 0; jj < 4; ++jj) {
            const int c = (c4 + 8 * jj) * 4;
            float4 x = *reinterpret_cast<const float4*>(src + c);
            Vs[r][c + 0] = (__bf16)x.x; Vs[r][c + 1] = (__bf16)x.y;
            Vs[r][c + 2] = (__bf16)x.z; Vs[r][c + 3] = (__bf16)x.w;
        }
    }
    __syncthreads();
    const int lane = tid & 63, w = tid >> 6;
    const int g = lane >> 4, li = lane & 15;
    bf16x8* dst = vf + ((size_t)b * NKBLK + kblk) * 8 * 64;
    #pragma unroll
    for (int jj = 0; jj < 2; ++jj) {
        const int dt = 2 * w + jj;
        bf16x8 v;
        #pragma unroll
        for (int e = 0; e < 8; ++e) v[e] = Vs[g * 8 + e][dt * 16 + li];
        dst[dt * 64 + lane] = v;
    }
}

// ============ preproc: mask -> per-wave bytes mp[b][qt16][kblk][lane] ============
// bit (t*4+r) = mask[b][qt16*16 + g*4 + r][kblk*32 + t*16 + li]
__global__ __launch_bounds__(256)
void pack_mask_kernel(const int* __restrict__ maskg, unsigned char* __restrict__ mp) {
    __shared__ unsigned ball[16][64];   // [q][k/32]
    const int tid  = threadIdx.x;
    const int wave = tid >> 6;
    const int lane = tid & 63;
    const int g    = lane >> 4;
    const int li   = lane & 15;
    const int qt   = blockIdx.x;   // 0..127
    const int b    = blockIdx.y;

    const int* mb = maskg + ((size_t)b * LSEQ + qt * 16) * LSEQ;
    #pragma unroll
    for (int qq = 0; qq < 4; ++qq) {
        const int q = wave * 4 + qq;
        #pragma unroll 8
        for (int c = 0; c < 32; ++c) {
            int m = mb[(size_t)q * LSEQ + c * 64 + lane];
            unsigned long long bal = __ballot(m != 0);
            if (lane == 0) {
                ball[q][c * 2]     = (unsigned)bal;
                ball[q][c * 2 + 1] = (unsigned)(bal >> 32);
            }
        }
    }
    __syncthreads();
    unsigned char* out = mp + ((size_t)b * 128 + qt) * (NKBLK * 64) + lane;
    for (int kb2 = wave; kb2 < NKBLK; kb2 += 4) {
        unsigned byte = 0;
        #pragma unroll
        for (int r = 0; r < 4; ++r) {
            unsigned wd = ball[g * 4 + r][kb2];
            byte |= ((wd >> li) & 1u) << r;
            byte |= ((wd >> (16 + li)) & 1u) << (4 + r);
        }
        out[(size_t)kb2 * 64] = (unsigned char)byte;
    }
}

// ============ attn_lds: LDS-staged K/V, 4 waves x 16q, blocked E dump ============
__global__ __launch_bounds__(256, 2)
void attn_lds(const float* __restrict__ qg,
              const bf16x8* __restrict__ kf,
              const bf16x8* __restrict__ vf,
              const unsigned char* __restrict__ mpk,
              float* __restrict__ og,
              float* __restrict__ rowinv_ws,
              __bf16* __restrict__ Eg)
{
    __shared__ bf16x8 Kst[512];                        // 8 KB
    __shared__ bf16x8 Vst[512];                        // 8 KB
    __shared__ __align__(16) __bf16 P[4][16][40];      // 5.1 KB

    const int tid  = threadIdx.x;
    const int wave = tid >> 6;     // 0..3
    const int lane = tid & 63;
    const int g    = lane >> 4;
    const int li   = lane & 15;

    // XCD pinning: batch b -> xcd b%8
    const int wgid = blockIdx.x;           // 0..511
    const int xcd  = wgid & 7;
    const int rest = wgid >> 3;            // 0..63
    const int b    = xcd + 8 * (rest & 1);
    const int qb   = rest >> 1;            // 0..31 (64-query block)
    const int q0   = qb * 64 + wave * 16;  // this wave's 16 queries
    const int qt16 = qb * 4 + wave;

    const size_t bb = (size_t)b * LSEQ;

    // Q fragments with scale*log2(e)
    const float qscale = 0.08838834764831845f * 1.4426950408889634f;
    bf16x8 qf[4];
    {
        const float* qrow = qg + (bb + q0 + li) * DIM + g * 8;
        #pragma unroll
        for (int d = 0; d < 4; ++d) {
            const float4* p4 = reinterpret_cast<const float4*>(qrow + d * 32);
            float4 x = p4[0];
            float4 y = p4[1];
            x.x *= qscale; x.y *= qscale; x.z *= qscale; x.w *= qscale;
            y.x *= qscale; y.y *= qscale; y.z *= qscale; y.w *= qscale;
            qf[d] = cvt8(x, y);
        }
    }

    float rsum[4] = {0.f, 0.f, 0.f, 0.f};
    f32x4 accO[8];
    #pragma unroll
    for (int i = 0; i < 8; ++i) accO[i] = (f32x4){0.f, 0.f, 0.f, 0.f};

    const bf16x8* KbU = kf + (size_t)b * NKBLK * 512;
    const bf16x8* VbU = vf + (size_t)b * NKBLK * 512;
    const unsigned char* mpb = mpk + ((size_t)b * 128 + qt16) * (NKBLK * 64) + lane;
    __bf16* Ebase = Eg + (((size_t)b * 128 + qt16) * (size_t)64) * 512 + lane * 8;

    // prologue: issue loads for tile 0 (T14: issue-early, ds_write-late)
    bf16x8 ka = KbU[tid], kb2 = KbU[256 + tid];
    bf16x8 va = VbU[tid], vb2 = VbU[256 + tid];
    unsigned mc = mpb[0], mn = 0;

    for (int t = 0; t < NKBLK; ++t) {
        // stage write (compiler waits vmcnt for the 4 staged regs only)
        Kst[tid] = ka; Kst[256 + tid] = kb2;
        Vst[tid] = va; Vst[256 + tid] = vb2;
        __syncthreads();                    // tile t visible to all waves

        // conflict-free contiguous b128 frag reads
        bf16x8 kc[8], vc[8];
        #pragma unroll
        for (int j = 0; j < 8; ++j) kc[j] = Kst[j * 64 + lane];
        #pragma unroll
        for (int j = 0; j < 8; ++j) vc[j] = Vst[j * 64 + lane];

        // issue loads for tile t+1 (fly during compute; consumed next iter)
        if (t + 1 < NKBLK) {
            const size_t un = (size_t)(t + 1) * 512;
            ka  = KbU[un + tid];       kb2 = KbU[un + 256 + tid];
            va  = VbU[un + tid];       vb2 = VbU[un + 256 + tid];
            mn  = mpb[(size_t)(t + 1) * 64];
        }
        __syncthreads();                    // all frag reads done (lgkm drained)

        // ---- QK^T
        f32x4 s0 = (f32x4){0.f, 0.f, 0.f, 0.f};
        f32x4 s1 = (f32x4){0.f, 0.f, 0.f, 0.f};
        #pragma unroll
        for (int d = 0; d < 4; ++d) {
            s0 = __builtin_amdgcn_mfma_f32_16x16x32_bf16(qf[d], kc[d],     s0, 0, 0, 0);
            s1 = __builtin_amdgcn_mfma_f32_16x16x32_bf16(qf[d], kc[4 + d], s1, 0, 0, 0);
        }

        // ---- mask + exp2 + P stage + rowsum
        #pragma unroll
        for (int t2 = 0; t2 < 2; ++t2) {
            f32x4 sv = t2 ? s1 : s0;
            #pragma unroll
            for (int r = 0; r < 4; ++r) {
                float sc = ((mc >> (t2 * 4 + r)) & 1u) ? -1.0e9f : sv[r];
                float ev = __builtin_amdgcn_exp2f(sc);
                rsum[r] += ev;
                P[wave][g * 4 + r][t2 * 16 + li] = (__bf16)ev;
            }
        }

        // ---- blocked E dump (contiguous 1KB per wave-tile, nt)
        {
            bf16x8 ed = *reinterpret_cast<const bf16x8*>(&P[wave][lane >> 2][(lane & 3) * 8]);
            __builtin_nontemporal_store(ed, reinterpret_cast<bf16x8*>(Ebase + (size_t)t * 512));
        }

        // ---- PV
        {
            bf16x8 af = *reinterpret_cast<const bf16x8*>(&P[wave][li][g * 8]);
            #pragma unroll
            for (int dt = 0; dt < 8; ++dt)
                accO[dt] = __builtin_amdgcn_mfma_f32_16x16x32_bf16(af, vc[dt], accO[dt], 0, 0, 0);
        }

        mc = mn;
    }

    // ---- per-wave rowsum reduce across li lanes
    #pragma unroll
    for (int off = 1; off < 16; off <<= 1) {
        #pragma unroll
        for (int r = 0; r < 4; ++r) rsum[r] += __shfl_xor(rsum[r], off, 64);
    }
    float rinv[4];
    #pragma unroll
    for (int r = 0; r < 4; ++r) rinv[r] = 1.0f / rsum[r];

    if (li == 0) {
        #pragma unroll
        for (int r = 0; r < 4; ++r)
            rowinv_ws[bb + q0 + g * 4 + r] = rinv[r];
    }

    // ---- O write (64B row segments, nt)
    {
        float* ob = og + (bb + q0) * DIM;
        #pragma unroll
        for (int dt = 0; dt < 8; ++dt)
            #pragma unroll
            for (int r = 0; r < 4; ++r)
                __builtin_nontemporal_store(accO[dt][r] * rinv[r],
                    ob + (size_t)(g * 4 + r) * DIM + dt * 16 + li);
    }
}

// ============ wstream v3: blocked E -> row-major W, register-only ============
__global__ __launch_bounds__(256)
void wstream(const __bf16* __restrict__ Eg,
             const float* __restrict__ rowinv_ws,
             float* __restrict__ wg)
{
    // unit u (16B of E): lane6=u&63, kblk=(u>>6)&63, qt16=(u>>12)&127, b=u>>19
    const size_t stride = (size_t)gridDim.x * 256;
    size_t u = (size_t)blockIdx.x * 256 + threadIdx.x;
    const size_t total = (size_t)BATCH * 128 * 64 * 64;
    for (; u < total; u += stride) {
        const int lane6 = (int)(u & 63);
        const int kblk  = (int)((u >> 6) & 63);
        const int qt16  = (int)((u >> 12) & 127);
        const int b     = (int)(u >> 19);
        const int qrow  = qt16 * 16 + (lane6 >> 2);
        const int col   = kblk * 32 + (lane6 & 3) * 8;
        const float inv = rowinv_ws[(size_t)b * LSEQ + qrow];
        bf16x8 e = __builtin_nontemporal_load(
            reinterpret_cast<const bf16x8*>(Eg + u * 8));
        f32x4 w0, w1;
        w0[0] = (float)e[0] * inv; w0[1] = (float)e[1] * inv;
        w0[2] = (float)e[2] * inv; w0[3] = (float)e[3] * inv;
        w1[0] = (float)e[4] * inv; w1[1] = (float)e[5] * inv;
        w1[2] = (float)e[6] * inv; w1[3] = (float)e[7] * inv;
        float* dst = wg + ((size_t)b * LSEQ + qrow) * LSEQ + col;
        __builtin_nontemporal_store(w0, reinterpret_cast<f32x4*>(dst));
        __builtin_nontemporal_store(w1, reinterpret_cast<f32x4*>(dst + 4));
    }
}

// ========================= fallback (no workspace) =========================
__global__ __launch_bounds__(256, 2)
void sdpa_fused_plain(const float* __restrict__ qg,
                      const float* __restrict__ kg,
                      const float* __restrict__ vg,
                      const int*   __restrict__ maskg,
                      float* __restrict__ og,
                      float* __restrict__ wg)
{
    __shared__ __align__(16) __bf16 Es[16 * EPITCH];
    __shared__ float Osum[16 * DIM];
    __shared__ float rowpart[4][16];
    __shared__ float rowinv[16];

    const int tid  = threadIdx.x;
    const int wave = tid >> 6;
    const int lane = tid & 63;
    const int g    = lane >> 4;
    const int li   = lane & 15;
    const int qt = blockIdx.x;
    const int b  = blockIdx.y;
    const int q0 = qt * 16;

    for (int i = tid; i < 16 * DIM; i += 256) Osum[i] = 0.0f;

    const float qscale = 0.08838834764831845f * 1.4426950408889634f;
    bf16x8 qf[4];
    {
        const float* qrow = qg + ((size_t)b * LSEQ + q0 + li) * DIM + g * 8;
        #pragma unroll
        for (int d = 0; d < 4; ++d) {
            const float4* p4 = reinterpret_cast<const float4*>(qrow + d * 32);
            float4 x = p4[0];
            float4 y = p4[1];
            x.x *= qscale; x.y *= qscale; x.z *= qscale; x.w *= qscale;
            y.x *= qscale; y.y *= qscale; y.z *= qscale; y.w *= qscale;
            qf[d] = cvt8(x, y);
        }
    }

    float rsum[4] = {0.f, 0.f, 0.f, 0.f};
    f32x4 accO[8];
    #pragma unroll
    for (int i = 0; i < 8; ++i) accO[i] = (f32x4){0.f, 0.f, 0.f, 0.f};

    const int kwave0 = wave * 512;
    const size_t browbase = (size_t)b * LSEQ;

    for (int it = 0; it < 16; ++it) {
        const int kb = kwave0 + it * 32;
        f32x4 s0 = (f32x4){0.f, 0.f, 0.f, 0.f};
        f32x4 s1 = (f32x4){0.f, 0.f, 0.f, 0.f};
        {
            const float* kp0 = kg + (browbase + kb + li) * DIM + g * 8;
            const float* kp1 = kp0 + (size_t)16 * DIM;
            #pragma unroll
            for (int d = 0; d < 4; ++d) {
                const float4* a4 = reinterpret_cast<const float4*>(kp0 + d * 32);
                const float4* b4 = reinterpret_cast<const float4*>(kp1 + d * 32);
                s0 = __builtin_amdgcn_mfma_f32_16x16x32_bf16(qf[d], cvt8(a4[0], a4[1]), s0, 0, 0, 0);
                s1 = __builtin_amdgcn_mfma_f32_16x16x32_bf16(qf[d], cvt8(b4[0], b4[1]), s1, 0, 0, 0);
            }
        }
        const int* mbase = maskg + (browbase + q0) * LSEQ + kb + li;
        #pragma unroll
        for (int t = 0; t < 2; ++t) {
            f32x4 sv = t ? s1 : s0;
            const int col = kb + t * 16 + li;
            #pragma unroll
            for (int r = 0; r < 4; ++r) {
                const int m = mbase[(size_t)(g * 4 + r) * LSEQ + t * 16];
                float sc = m ? -1.0e9f : sv[r];
                float ev = __builtin_amdgcn_exp2f(sc);
                rsum[r] += ev;
                Es[(g * 4 + r) * EPITCH + col] = (__bf16)ev;
            }
        }
        bf16x8 af = *reinterpret_cast<const bf16x8*>(&Es[li * EPITCH + kb + g * 8]);
        const float* vb = vg + (browbase + kb + g * 8) * DIM + li;
        #pragma unroll
        for (int dt = 0; dt < 8; ++dt) {
            const float* vp = vb + dt * 16;
            bf16x8 bf;
            #pragma unroll
            for (int j = 0; j < 8; ++j) bf[j] = (__bf16)vp[(size_t)j * DIM];
            accO[dt] = __builtin_amdgcn_mfma_f32_16x16x32_bf16(af, bf, accO[dt], 0, 0, 0);
        }
    }

    #pragma unroll
    for (int off = 1; off < 16; off <<= 1) {
        #pragma unroll
        for (int r = 0; r < 4; ++r) rsum[r] += __shfl_xor(rsum[r], off, 64);
    }
    if (li == 0) {
        #pragma unroll
        for (int r = 0; r < 4; ++r) rowpart[wave][g * 4 + r] = rsum[r];
    }
    __syncthreads();
    #pragma unroll
    for (int dt = 0; dt < 8; ++dt) {
        #pragma unroll
        for (int r = 0; r < 4; ++r)
            atomicAdd(&Osum[(g * 4 + r) * DIM + dt * 16 + li], accO[dt][r]);
    }
    if (tid < 16) {
        float s = rowpart[0][tid] + rowpart[1][tid] + rowpart[2][tid] + rowpart[3][tid];
        rowinv[tid] = 1.0f / s;
    }
    __syncthreads();

    const size_t wbase = (browbase + q0) * LSEQ;
    for (int i = tid; i < 16 * (LSEQ / 8); i += 256) {
        const int row = i >> 8;
        const int col = (i & 255) * 8;
        bf16x8 e = *reinterpret_cast<const bf16x8*>(&Es[row * EPITCH + col]);
        const float inv = rowinv[row];
        float4 w0, w1;
        w0.x = (float)e[0] * inv; w0.y = (float)e[1] * inv;
        w0.z = (float)e[2] * inv; w0.w = (float)e[3] * inv;
        w1.x = (float)e[4] * inv; w1.y = (float)e[5] * inv;
        w1.z = (float)e[6] * inv; w1.w = (float)e[7] * inv;
        float* dst = wg + wbase + (size_t)row * LSEQ + col;
        *reinterpret_cast<float4*>(dst)     = w0;
        *reinterpret_cast<float4*>(dst + 4) = w1;
    }
    const size_t obase = (browbase + q0) * DIM;
    for (int i = tid; i < 16 * DIM; i += 256) {
        const int row = i >> 7;
        og[obase + i] = Osum[i] * rowinv[row];
    }
}

extern "C" void kernel_launch(void* const* d_in, const int* in_sizes, int n_in,
                              void* d_out, int out_size, void* d_ws, size_t ws_size,
                              hipStream_t stream) {
    const float* q    = (const float*)d_in[0];
    const float* k    = (const float*)d_in[1];
    const float* v    = (const float*)d_in[2];
    const int*   mask = (const int*)d_in[3];
    float* o = (float*)d_out;
    float* w = (float*)d_out + (size_t)BATCH * LSEQ * DIM;

    const size_t kfSize = (size_t)BATCH * NKBLK * 8 * 64 * sizeof(bf16x8);   // 8.4 MB
    const size_t vfSize = kfSize;                                            // 8.4 MB
    const size_t mpSize = (size_t)BATCH * 128 * NKBLK * 64;                  // 8.4 MB
    const size_t riSize = (size_t)BATCH * LSEQ * sizeof(float);              // 131 KB
    const size_t eSize  = (size_t)BATCH * LSEQ * LSEQ * sizeof(__bf16);      // 134 MB
    const size_t need   = kfSize + vfSize + mpSize + riSize + eSize;

    if (ws_size >= need) {
        bf16x8* kf = (bf16x8*)d_ws;
        bf16x8* vfp = (bf16x8*)((char*)d_ws + kfSize);
        unsigned char* mp = (unsigned char*)((char*)d_ws + kfSize + vfSize);
        float* ri = (float*)((char*)d_ws + kfSize + vfSize + mpSize);
        __bf16* Eg = (__bf16*)((char*)d_ws + kfSize + vfSize + mpSize + riSize);
        pack_k_kernel<<<dim3(NKBLK, BATCH), 256, 0, stream>>>(k, kf);
        pack_v_kernel<<<dim3(NKBLK, BATCH), 256, 0, stream>>>(v, vfp);
        pack_mask_kernel<<<dim3(128, BATCH), 256, 0, stream>>>(mask, mp);
        attn_lds<<<512, 256, 0, stream>>>(q, kf, vfp, mp, o, ri, Eg);
        wstream<<<4096, 256, 0, stream>>>(Eg, ri, w);
    } else {
        dim3 grid(LSEQ / 16, BATCH);
        sdpa_fused_plain<<<grid, 256, 0, stream>>>(q, k, v, mask, o, w);
    }
}

// Round 10
// 207.138 us; speedup vs baseline: 2.4821x; 1.2602x over previous
//
#include <hip/hip_runtime.h>
#include <hip/hip_bf16.h>

typedef __attribute__((ext_vector_type(8))) __bf16 bf16x8;
typedef __attribute__((ext_vector_type(4))) float f32x4;

#define BATCH 16
#define LSEQ 2048
#define DIM 128
#define EPITCH 2056
#define NKBLK 64   // 2048 / 32

__device__ __forceinline__ bf16x8 cvt8(float4 a, float4 b) {
    bf16x8 r;
    r[0] = (__bf16)a.x; r[1] = (__bf16)a.y; r[2] = (__bf16)a.z; r[3] = (__bf16)a.w;
    r[4] = (__bf16)b.x; r[5] = (__bf16)b.y; r[6] = (__bf16)b.z; r[7] = (__bf16)b.w;
    return r;
}

// ============ preproc: K -> fragment-blocked Kf[b][kblk][j][lane] ============
// j = t*4+d ; lane = g*16+li ; unit (bf16x8) = K[b][kblk*32 + t*16 + li][d*32 + g*8 + e]
__global__ __launch_bounds__(256)
void pack_k_kernel(const float* __restrict__ kg, bf16x8* __restrict__ kf) {
    __shared__ __bf16 Ks[32][DIM + 8];
    const int kblk = blockIdx.x, b = blockIdx.y;
    const int tid = threadIdx.x;
    {
        const int r = tid >> 3, c4 = tid & 7;
        const float* src = kg + ((size_t)b * LSEQ + kblk * 32 + r) * DIM;
        #pragma unroll
        for (int jj = 0; jj < 4; ++jj) {
            const int c = (c4 + 8 * jj) * 4;
            float4 x = *reinterpret_cast<const float4*>(src + c);
            Ks[r][c + 0] = (__bf16)x.x; Ks[r][c + 1] = (__bf16)x.y;
            Ks[r][c + 2] = (__bf16)x.z; Ks[r][c + 3] = (__bf16)x.w;
        }
    }
    __syncthreads();
    const int lane = tid & 63, w = tid >> 6;
    const int g = lane >> 4, li = lane & 15;
    bf16x8* dst = kf + ((size_t)b * NKBLK + kblk) * 8 * 64;
    #pragma unroll
    for (int jj = 0; jj < 2; ++jj) {
        const int j = 2 * w + jj;
        const int t = j >> 2, d = j & 3;
        bf16x8 v;
        #pragma unroll
        for (int e = 0; e < 8; ++e) v[e] = Ks[t * 16 + li][d * 32 + g * 8 + e];
        dst[j * 64 + lane] = v;
    }
}

// ============ preproc: V -> fragment-blocked Vf[b][kblk][dt][lane] ============
// unit (bf16x8) = V[b][kblk*32 + g*8 + e][dt*16 + li]
__global__ __launch_bounds__(256)
void pack_v_kernel(const float* __restrict__ vg, bf16x8* __restrict__ vf) {
    __shared__ __bf16 Vs[32][DIM + 8];
    const int kblk = blockIdx.x, b = blockIdx.y;
    const int tid = threadIdx.x;
    {
        const int r = tid >> 3, c4 = tid & 7;
        const float* src = vg + ((size_t)b * LSEQ + kblk * 32 + r) * DIM;
        #pragma unroll
        for (int jj = 0; jj < 4; ++jj) {
            const int c = (c4 + 8 * jj) * 4;
            float4 x = *reinterpret_cast<const float4*>(src + c);
            Vs[r][c + 0] = (__bf16)x.x; Vs[r][c + 1] = (__bf16)x.y;
            Vs[r][c + 2] = (__bf16)x.z; Vs[r][c + 3] = (__bf16)x.w;
        }
    }
    __syncthreads();
    const int lane = tid & 63, w = tid >> 6;
    const int g = lane >> 4, li = lane & 15;
    bf16x8* dst = vf + ((size_t)b * NKBLK + kblk) * 8 * 64;
    #pragma unroll
    for (int jj = 0; jj < 2; ++jj) {
        const int dt = 2 * w + jj;
        bf16x8 v;
        #pragma unroll
        for (int e = 0; e < 8; ++e) v[e] = Vs[g * 8 + e][dt * 16 + li];
        dst[dt * 64 + lane] = v;
    }
}

// ============ attn_fused: 2-pass (rowsum+O, then W recompute), no E buffer ============
__global__ __launch_bounds__(256, 2)
void attn_fused(const float* __restrict__ qg,
                const bf16x8* __restrict__ kf,
                const bf16x8* __restrict__ vf,
                const int* __restrict__ maskg,
                float* __restrict__ og,
                float* __restrict__ wg)
{
    __shared__ bf16x8 Kst[512];                        // 8 KB
    __shared__ bf16x8 Vst[512];                        // 8 KB
    __shared__ __align__(16) __bf16 P[4][16][40];      // 5.1 KB
    __shared__ unsigned char MB[4][NKBLK][64];         // 16 KB mask bytes for pass 2

    const int tid  = threadIdx.x;
    const int wave = tid >> 6;     // 0..3
    const int lane = tid & 63;
    const int g    = lane >> 4;
    const int li   = lane & 15;

    // XCD pinning: batch b -> xcd b%8
    const int wgid = blockIdx.x;           // 0..511
    const int xcd  = wgid & 7;
    const int rest = wgid >> 3;            // 0..63
    const int b    = xcd + 8 * (rest & 1);
    const int qb   = rest >> 1;            // 0..31 (64-query block)
    const int q0   = qb * 64 + wave * 16;  // this wave's 16 queries

    const size_t bb = (size_t)b * LSEQ;

    // Q fragments with scale*log2(e)
    const float qscale = 0.08838834764831845f * 1.4426950408889634f;
    bf16x8 qf[4];
    {
        const float* qrow = qg + (bb + q0 + li) * DIM + g * 8;
        #pragma unroll
        for (int d = 0; d < 4; ++d) {
            const float4* p4 = reinterpret_cast<const float4*>(qrow + d * 32);
            float4 x = p4[0];
            float4 y = p4[1];
            x.x *= qscale; x.y *= qscale; x.z *= qscale; x.w *= qscale;
            y.x *= qscale; y.y *= qscale; y.z *= qscale; y.w *= qscale;
            qf[d] = cvt8(x, y);
        }
    }

    float rsum[4] = {0.f, 0.f, 0.f, 0.f};
    f32x4 accO[8];
    #pragma unroll
    for (int i = 0; i < 8; ++i) accO[i] = (f32x4){0.f, 0.f, 0.f, 0.f};

    const bf16x8* KbU = kf + (size_t)b * NKBLK * 512;
    const bf16x8* VbU = vf + (size_t)b * NKBLK * 512;
    // mask in fragment order: element (t2,r) at iter t = mpQ[r*LSEQ + t*32 + t2*16]
    const int* mpQ = maskg + (bb + q0 + g * 4) * (size_t)LSEQ + li;

    // ================= PASS 1: rowsum + PV + O =================
    bf16x8 ka = KbU[tid], kb2 = KbU[256 + tid];
    bf16x8 va = VbU[tid], vb2 = VbU[256 + tid];
    int mcur[8], mnxt[8];
    #pragma unroll
    for (int j = 0; j < 8; ++j) {
        const int t2 = j >> 2, r = j & 3;
        mcur[j] = mpQ[(size_t)r * LSEQ + t2 * 16];
    }

    for (int t = 0; t < NKBLK; ++t) {
        Kst[tid] = ka; Kst[256 + tid] = kb2;
        Vst[tid] = va; Vst[256 + tid] = vb2;
        __syncthreads();

        bf16x8 kc[8], vc[8];
        #pragma unroll
        for (int j = 0; j < 8; ++j) kc[j] = Kst[j * 64 + lane];
        #pragma unroll
        for (int j = 0; j < 8; ++j) vc[j] = Vst[j * 64 + lane];

        // prefetch tile t+1 (K, V, mask)
        if (t + 1 < NKBLK) {
            const size_t un = (size_t)(t + 1) * 512;
            ka = KbU[un + tid];  kb2 = KbU[un + 256 + tid];
            va = VbU[un + tid];  vb2 = VbU[un + 256 + tid];
            #pragma unroll
            for (int j = 0; j < 8; ++j) {
                const int t2 = j >> 2, r = j & 3;
                mnxt[j] = mpQ[(size_t)r * LSEQ + (t + 1) * 32 + t2 * 16];
            }
        }
        __syncthreads();

        // QK^T
        f32x4 s0 = (f32x4){0.f, 0.f, 0.f, 0.f};
        f32x4 s1 = (f32x4){0.f, 0.f, 0.f, 0.f};
        #pragma unroll
        for (int d = 0; d < 4; ++d) {
            s0 = __builtin_amdgcn_mfma_f32_16x16x32_bf16(qf[d], kc[d],     s0, 0, 0, 0);
            s1 = __builtin_amdgcn_mfma_f32_16x16x32_bf16(qf[d], kc[4 + d], s1, 0, 0, 0);
        }

        // mask + exp2 + P stage + rowsum; pack byte for pass 2
        unsigned byte = 0;
        #pragma unroll
        for (int t2 = 0; t2 < 2; ++t2) {
            f32x4 sv = t2 ? s1 : s0;
            #pragma unroll
            for (int r = 0; r < 4; ++r) {
                const int j = t2 * 4 + r;
                const bool msk = (mcur[j] != 0);
                byte |= (msk ? 1u : 0u) << j;
                float sc = msk ? -1.0e9f : sv[r];
                float ev = __builtin_amdgcn_exp2f(sc);
                rsum[r] += ev;
                P[wave][g * 4 + r][t2 * 16 + li] = (__bf16)ev;
            }
        }
        MB[wave][t][lane] = (unsigned char)byte;

        // PV
        {
            bf16x8 af = *reinterpret_cast<const bf16x8*>(&P[wave][li][g * 8]);
            #pragma unroll
            for (int dt = 0; dt < 8; ++dt)
                accO[dt] = __builtin_amdgcn_mfma_f32_16x16x32_bf16(af, vc[dt], accO[dt], 0, 0, 0);
        }

        #pragma unroll
        for (int j = 0; j < 8; ++j) mcur[j] = mnxt[j];
    }

    // per-wave rowsum reduce across li lanes
    #pragma unroll
    for (int off = 1; off < 16; off <<= 1) {
        #pragma unroll
        for (int r = 0; r < 4; ++r) rsum[r] += __shfl_xor(rsum[r], off, 64);
    }
    float rinv[4];
    #pragma unroll
    for (int r = 0; r < 4; ++r) rinv[r] = 1.0f / rsum[r];

    // O write (nt)
    {
        float* ob = og + (bb + q0) * DIM;
        #pragma unroll
        for (int dt = 0; dt < 8; ++dt)
            #pragma unroll
            for (int r = 0; r < 4; ++r)
                __builtin_nontemporal_store(accO[dt][r] * rinv[r],
                    ob + (size_t)(g * 4 + r) * DIM + dt * 16 + li);
    }

    // ================= PASS 2: recompute QK^T, write W =================
    ka = KbU[tid]; kb2 = KbU[256 + tid];
    float* wrow = wg + (bb + q0) * (size_t)LSEQ;

    for (int t = 0; t < NKBLK; ++t) {
        Kst[tid] = ka; Kst[256 + tid] = kb2;
        __syncthreads();

        bf16x8 kc[8];
        #pragma unroll
        for (int j = 0; j < 8; ++j) kc[j] = Kst[j * 64 + lane];
        const unsigned byte = MB[wave][t][lane];   // same-wave LDS, in-order

        if (t + 1 < NKBLK) {
            const size_t un = (size_t)(t + 1) * 512;
            ka = KbU[un + tid];  kb2 = KbU[un + 256 + tid];
        }
        __syncthreads();

        f32x4 s0 = (f32x4){0.f, 0.f, 0.f, 0.f};
        f32x4 s1 = (f32x4){0.f, 0.f, 0.f, 0.f};
        #pragma unroll
        for (int d = 0; d < 4; ++d) {
            s0 = __builtin_amdgcn_mfma_f32_16x16x32_bf16(qf[d], kc[d],     s0, 0, 0, 0);
            s1 = __builtin_amdgcn_mfma_f32_16x16x32_bf16(qf[d], kc[4 + d], s1, 0, 0, 0);
        }

        #pragma unroll
        for (int t2 = 0; t2 < 2; ++t2) {
            f32x4 sv = t2 ? s1 : s0;
            const int col = t * 32 + t2 * 16 + li;
            #pragma unroll
            for (int r = 0; r < 4; ++r) {
                float sc = ((byte >> (t2 * 4 + r)) & 1u) ? -1.0e9f : sv[r];
                float ev = __builtin_amdgcn_exp2f(sc);
                __builtin_nontemporal_store(ev * rinv[r],
                    wrow + (size_t)(g * 4 + r) * LSEQ + col);
            }
        }
    }
}

// ========================= fallback (no workspace) =========================
__global__ __launch_bounds__(256, 2)
void sdpa_fused_plain(const float* __restrict__ qg,
                      const float* __restrict__ kg,
                      const float* __restrict__ vg,
                      const int*   __restrict__ maskg,
                      float* __restrict__ og,
                      float* __restrict__ wg)
{
    __shared__ __align__(16) __bf16 Es[16 * EPITCH];
    __shared__ float Osum[16 * DIM];
    __shared__ float rowpart[4][16];
    __shared__ float rowinv[16];

    const int tid  = threadIdx.x;
    const int wave = tid >> 6;
    const int lane = tid & 63;
    const int g    = lane >> 4;
    const int li   = lane & 15;
    const int qt = blockIdx.x;
    const int b  = blockIdx.y;
    const int q0 = qt * 16;

    for (int i = tid; i < 16 * DIM; i += 256) Osum[i] = 0.0f;

    const float qscale = 0.08838834764831845f * 1.4426950408889634f;
    bf16x8 qf[4];
    {
        const float* qrow = qg + ((size_t)b * LSEQ + q0 + li) * DIM + g * 8;
        #pragma unroll
        for (int d = 0; d < 4; ++d) {
            const float4* p4 = reinterpret_cast<const float4*>(qrow + d * 32);
            float4 x = p4[0];
            float4 y = p4[1];
            x.x *= qscale; x.y *= qscale; x.z *= qscale; x.w *= qscale;
            y.x *= qscale; y.y *= qscale; y.z *= qscale; y.w *= qscale;
            qf[d] = cvt8(x, y);
        }
    }

    float rsum[4] = {0.f, 0.f, 0.f, 0.f};
    f32x4 accO[8];
    #pragma unroll
    for (int i = 0; i < 8; ++i) accO[i] = (f32x4){0.f, 0.f, 0.f, 0.f};

    const int kwave0 = wave * 512;
    const size_t browbase = (size_t)b * LSEQ;

    for (int it = 0; it < 16; ++it) {
        const int kb = kwave0 + it * 32;
        f32x4 s0 = (f32x4){0.f, 0.f, 0.f, 0.f};
        f32x4 s1 = (f32x4){0.f, 0.f, 0.f, 0.f};
        {
            const float* kp0 = kg + (browbase + kb + li) * DIM + g * 8;
            const float* kp1 = kp0 + (size_t)16 * DIM;
            #pragma unroll
            for (int d = 0; d < 4; ++d) {
                const float4* a4 = reinterpret_cast<const float4*>(kp0 + d * 32);
                const float4* b4 = reinterpret_cast<const float4*>(kp1 + d * 32);
                s0 = __builtin_amdgcn_mfma_f32_16x16x32_bf16(qf[d], cvt8(a4[0], a4[1]), s0, 0, 0, 0);
                s1 = __builtin_amdgcn_mfma_f32_16x16x32_bf16(qf[d], cvt8(b4[0], b4[1]), s1, 0, 0, 0);
            }
        }
        const int* mbase = maskg + (browbase + q0) * LSEQ + kb + li;
        #pragma unroll
        for (int t = 0; t < 2; ++t) {
            f32x4 sv = t ? s1 : s0;
            const int col = kb + t * 16 + li;
            #pragma unroll
            for (int r = 0; r < 4; ++r) {
                const int m = mbase[(size_t)(g * 4 + r) * LSEQ + t * 16];
                float sc = m ? -1.0e9f : sv[r];
                float ev = __builtin_amdgcn_exp2f(sc);
                rsum[r] += ev;
                Es[(g * 4 + r) * EPITCH + col] = (__bf16)ev;
            }
        }
        bf16x8 af = *reinterpret_cast<const bf16x8*>(&Es[li * EPITCH + kb + g * 8]);
        const float* vb = vg + (browbase + kb + g * 8) * DIM + li;
        #pragma unroll
        for (int dt = 0; dt < 8; ++dt) {
            const float* vp = vb + dt * 16;
            bf16x8 bf;
            #pragma unroll
            for (int j = 0; j < 8; ++j) bf[j] = (__bf16)vp[(size_t)j * DIM];
            accO[dt] = __builtin_amdgcn_mfma_f32_16x16x32_bf16(af, bf, accO[dt], 0, 0, 0);
        }
    }

    #pragma unroll
    for (int off = 1; off < 16; off <<= 1) {
        #pragma unroll
        for (int r = 0; r < 4; ++r) rsum[r] += __shfl_xor(rsum[r], off, 64);
    }
    if (li == 0) {
        #pragma unroll
        for (int r = 0; r < 4; ++r) rowpart[wave][g * 4 + r] = rsum[r];
    }
    __syncthreads();
    #pragma unroll
    for (int dt = 0; dt < 8; ++dt) {
        #pragma unroll
        for (int r = 0; r < 4; ++r)
            atomicAdd(&Osum[(g * 4 + r) * DIM + dt * 16 + li], accO[dt][r]);
    }
    if (tid < 16) {
        float s = rowpart[0][tid] + rowpart[1][tid] + rowpart[2][tid] + rowpart[3][tid];
        rowinv[tid] = 1.0f / s;
    }
    __syncthreads();

    const size_t wbase = (browbase + q0) * LSEQ;
    for (int i = tid; i < 16 * (LSEQ / 8); i += 256) {
        const int row = i >> 8;
        const int col = (i & 255) * 8;
        bf16x8 e = *reinterpret_cast<const bf16x8*>(&Es[row * EPITCH + col]);
        const float inv = rowinv[row];
        float4 w0, w1;
        w0.x = (float)e[0] * inv; w0.y = (float)e[1] * inv;
        w0.z = (float)e[2] * inv; w0.w = (float)e[3] * inv;
        w1.x = (float)e[4] * inv; w1.y = (float)e[5] * inv;
        w1.z = (float)e[6] * inv; w1.w = (float)e[7] * inv;
        float* dst = wg + wbase + (size_t)row * LSEQ + col;
        *reinterpret_cast<float4*>(dst)     = w0;
        *reinterpret_cast<float4*>(dst + 4) = w1;
    }
    const size_t obase = (browbase + q0) * DIM;
    for (int i = tid; i < 16 * DIM; i += 256) {
        const int row = i >> 7;
        og[obase + i] = Osum[i] * rowinv[row];
    }
}

extern "C" void kernel_launch(void* const* d_in, const int* in_sizes, int n_in,
                              void* d_out, int out_size, void* d_ws, size_t ws_size,
                              hipStream_t stream) {
    const float* q    = (const float*)d_in[0];
    const float* k    = (const float*)d_in[1];
    const float* v    = (const float*)d_in[2];
    const int*   mask = (const int*)d_in[3];
    float* o = (float*)d_out;
    float* w = (float*)d_out + (size_t)BATCH * LSEQ * DIM;

    const size_t kfSize = (size_t)BATCH * NKBLK * 8 * 64 * sizeof(bf16x8);   // 8.4 MB
    const size_t vfSize = kfSize;                                            // 8.4 MB
    const size_t need   = kfSize + vfSize;                                   // 16.8 MB

    if (ws_size >= need) {
        bf16x8* kf  = (bf16x8*)d_ws;
        bf16x8* vfp = (bf16x8*)((char*)d_ws + kfSize);
        pack_k_kernel<<<dim3(NKBLK, BATCH), 256, 0, stream>>>(k, kf);
        pack_v_kernel<<<dim3(NKBLK, BATCH), 256, 0, stream>>>(v, vfp);
        attn_fused<<<512, 256, 0, stream>>>(q, kf, vfp, mask, o, w);
    } else {
        dim3 grid(LSEQ / 16, BATCH);
        sdpa_fused_plain<<<grid, 256, 0, stream>>>(q, k, v, mask, o, w);
    }
}